// Round 1
// baseline (120.604 us; speedup 1.0000x reference)
//
#include <hip/hip_runtime.h>

// Problem constants (fixed by reference setup): B=8, X=Y=Z=128, P=64.
#define BATCH     8
#define DIM       128
#define NVOX      (BATCH * DIM * DIM * DIM)       // 16,777,216 floats
#define NPERSON   64
#define THREADS   256
#define FLOATS_PER_BLOCK 8192                     // 2048 float4
#define NBLOCK1   (NVOX / FLOATS_PER_BLOCK)       // 2048 blocks, 256/batch
#define TSIZE     4096
#define EMPTYK    0xFFFFFFFFu

// ---------------------------------------------------------------------------
// Kernel 1: per-block partial sum of feature^2 (coalesced float4 loads).
// Block i covers contiguous floats [i*8192, (i+1)*8192) -> single batch each.
// Writes partials[i] unconditionally (d_ws poison-safe, no atomics).
// ---------------------------------------------------------------------------
__global__ __launch_bounds__(THREADS) void sumsq_kernel(
    const float* __restrict__ feature, float* __restrict__ partials)
{
    const int tid = threadIdx.x;
    const float4* f4 = (const float4*)feature;
    const size_t base = (size_t)blockIdx.x * (FLOATS_PER_BLOCK / 4);
    float acc = 0.f;
#pragma unroll
    for (int j = 0; j < 8; ++j) {
        float4 v = f4[base + (size_t)j * THREADS + tid];
        acc += v.x * v.x + v.y * v.y + v.z * v.z + v.w * v.w;
    }
    // wave (64-lane) shuffle reduce, then 4 waves via LDS
    for (int off = 32; off > 0; off >>= 1) acc += __shfl_down(acc, off, 64);
    __shared__ float wsum[4];
    const int lane = tid & 63, wave = tid >> 6;
    if (lane == 0) wsum[wave] = acc;
    __syncthreads();
    if (tid == 0) partials[blockIdx.x] = wsum[0] + wsum[1] + wsum[2] + wsum[3];
}

// ---------------------------------------------------------------------------
// Kernel 2: single block. Sparse heat/dilation bookkeeping + final losses.
// ---------------------------------------------------------------------------
__global__ __launch_bounds__(THREADS) void finalize_kernel(
    const float* __restrict__ feature,
    const float* __restrict__ batch_index,
    const float* __restrict__ person_pos,
    const float* __restrict__ min_loc,
    const float* __restrict__ delta,
    const float* __restrict__ partials,
    float* __restrict__ out)
{
    __shared__ unsigned keys[NPERSON];
    __shared__ int      uniq[NPERSON];
    __shared__ float    sS2[BATCH], sDil[BATCH], sCorr[BATCH], sPos[BATCH];
    __shared__ int      sNr[BATCH];
    __shared__ unsigned table[TSIZE];
    __shared__ float    red[4];

    const int tid = threadIdx.x;

    if (tid < BATCH) { sDil[tid] = 0.f; sCorr[tid] = 0.f; sPos[tid] = 0.f; sNr[tid] = 0; }
    for (int s = tid; s < TSIZE; s += THREADS) table[s] = EMPTYK;

    // --- person -> voxel key, matching numpy fp32 ops exactly ---
    if (tid < NPERSON) {
        const int p = tid;
        const int b = (int)(batch_index[p] + 0.5f);
        float vx = (person_pos[p * 3 + 0] - min_loc[0]) / delta[0];
        float vy = (person_pos[p * 3 + 1] - min_loc[1]) / delta[1];
        float vz = (person_pos[p * 3 + 2] - min_loc[2]) / delta[2];
        vx = fminf(fmaxf(vx, 0.f), (float)(DIM - 1));
        vy = fminf(fmaxf(vy, 0.f), (float)(DIM - 1));
        vz = fminf(fmaxf(vz, 0.f), (float)(DIM - 1));
        const int x = (int)(vx + 0.5f);
        const int y = (int)(vy + 0.5f);
        const int z = (int)(vz + 0.5f);
        keys[p] = ((unsigned)b << 21) | ((unsigned)x << 14) | ((unsigned)y << 7) | (unsigned)z;
    }
    __syncthreads();

    // --- dedup persons; nr_persons[b] counts distinct voxels ---
    if (tid < NPERSON) {
        int u = 1;
        for (int q = 0; q < tid; ++q)
            if (keys[q] == keys[tid]) { u = 0; break; }
        uniq[tid] = u;
        if (u) atomicAdd(&sNr[keys[tid] >> 21], 1);
    }
    __syncthreads();

    // --- insert 3x3x3 dilation neighborhood into hash (dedup via CAS) ---
    for (int w = tid; w < NPERSON * 27; w += THREADS) {
        const int p = w / 27;
        if (!uniq[p]) continue;
        const unsigned k = keys[p];
        const int o = w % 27;
        const int x = (int)((k >> 14) & 127) + (o / 9) - 1;
        const int y = (int)((k >> 7) & 127) + ((o / 3) % 3) - 1;
        const int z = (int)(k & 127) + (o % 3) - 1;
        if ((unsigned)x > (unsigned)(DIM - 1) || (unsigned)y > (unsigned)(DIM - 1) ||
            (unsigned)z > (unsigned)(DIM - 1)) continue;
        const unsigned nk = (k & (7u << 21)) | ((unsigned)x << 14) | ((unsigned)y << 7) | (unsigned)z;
        unsigned h = ((nk * 2654435761u) >> 16) & (TSIZE - 1);
        for (;;) {
            const unsigned old = atomicCAS(&table[h], EMPTYK, nk);
            if (old == EMPTYK || old == nk) break;
            h = (h + 1) & (TSIZE - 1);
        }
    }
    __syncthreads();

    // --- Sdil[b] = sum over dilated voxels of (f - heat)^2 ---
    for (int s = tid; s < TSIZE; s += THREADS) {
        const unsigned k = table[s];
        if (k == EMPTYK) continue;
        const int b = k >> 21;
        const int x = (k >> 14) & 127, y = (k >> 7) & 127, z = k & 127;
        const float f = feature[(((size_t)b * DIM + x) * DIM + y) * DIM + z];
        float heat = 0.f;
        for (int q = 0; q < NPERSON; ++q)
            if (keys[q] == k) { heat = 1.f; break; }
        const float d = f - heat;
        atomicAdd(&sDil[b], d * d);
    }

    // --- heat-voxel sums: Scorr = sum(1-2f), Spos = sum((f-1)^2) ---
    if (tid < NPERSON && uniq[tid]) {
        const unsigned k = keys[tid];
        const int b = k >> 21;
        const int x = (k >> 14) & 127, y = (k >> 7) & 127, z = k & 127;
        const float f = feature[(((size_t)b * DIM + x) * DIM + y) * DIM + z];
        atomicAdd(&sCorr[b], 1.f - 2.f * f);
        const float d = f - 1.f;
        atomicAdd(&sPos[b], d * d);
    }

    // --- reduce 256 partials per batch -> sS2[b] (also barriers the atomics) ---
    const int lane = tid & 63, wave = tid >> 6;
    for (int b = 0; b < BATCH; ++b) {
        float v = partials[b * (NBLOCK1 / BATCH) + tid];
        for (int off = 32; off > 0; off >>= 1) v += __shfl_down(v, off, 64);
        if (lane == 0) red[wave] = v;
        __syncthreads();
        if (tid == 0) sS2[b] = red[0] + red[1] + red[2] + red[3];
        __syncthreads();
    }

    // --- final per-batch loss ---
    if (tid < BATCH) {
        const int b = tid;
        const float nr = (float)sNr[b];
        const float N = (float)(DIM * DIM * DIM);
        const float scale_neg = nr * 27.f / N;
        const float scale_pos = 1.f - nr / N;
        const float neg = sS2[b] + sCorr[b] - sDil[b];
        out[b] = (scale_neg * neg + scale_pos * sPos[b]) / nr;
    }
}

extern "C" void kernel_launch(void* const* d_in, const int* in_sizes, int n_in,
                              void* d_out, int out_size, void* d_ws, size_t ws_size,
                              hipStream_t stream)
{
    const float* feature     = (const float*)d_in[0];
    const float* batch_index = (const float*)d_in[1];
    const float* person_pos  = (const float*)d_in[2];
    const float* min_loc     = (const float*)d_in[3];
    const float* delta       = (const float*)d_in[4];
    float* out = (float*)d_out;
    float* partials = (float*)d_ws;   // NBLOCK1 floats = 8 KB

    sumsq_kernel<<<NBLOCK1, THREADS, 0, stream>>>(feature, partials);
    finalize_kernel<<<1, THREADS, 0, stream>>>(feature, batch_index, person_pos,
                                               min_loc, delta, partials, out);
}